// Round 14
// baseline (455.262 us; speedup 1.0000x reference)
//
#include <hip/hip_runtime.h>

#define HID 128
#define NCHUNK 4   // source-node chunks; 12500 rows * 256 B = 3.2 MB < 4 MiB per-XCD L2
#define NXCD 8

typedef _Float16 half8 __attribute__((ext_vector_type(8)));
typedef _Float16 half4h __attribute__((ext_vector_type(4)));
typedef int int4v __attribute__((ext_vector_type(4)));
using float4v = __attribute__((ext_vector_type(4))) float;

// ---- async global->LDS, 16 B per lane (wave-uniform base + lane*16) ----
typedef const __attribute__((address_space(1))) unsigned int* gas_ptr;
typedef __attribute__((address_space(3))) unsigned int* las_ptr;
__device__ __forceinline__ void gld16(const void* g, void* l) {
    __builtin_amdgcn_global_load_lds((gas_ptr)g, (las_ptr)l, 16, 0, 0);
}

__device__ __forceinline__ int chunk_of(int s, int CH) {
    return (s >= CH) + (s >= 2 * CH) + (s >= 3 * CH);
}

// all 5 weight matrices transposed+converted: Wh[m*K+k] = W[k*M+m]
struct WSegs {
    const float* W[5];
    _Float16* H[5];
    int K[5], M[5], start[5];
};

// ---------------- FUSED1: per-(dst,chunk) deg count + x->fp16 + W transpose/convert ----------------
__global__ __launch_bounds__(256) void fused_prep1(
    const int* __restrict__ src, const int* __restrict__ dst,
    int* __restrict__ degc, int E, int nDeg, int CH,
    const float* __restrict__ x, _Float16* __restrict__ Xh, int total4, int nX,
    WSegs S, int totalW) {
    int bx = blockIdx.x;
    if (bx < nDeg) {
        int i = bx * 256 + (int)threadIdx.x;
        if (i < E) {
            int d = dst[i];
            int p = chunk_of(src[i], CH);
            atomicAdd(&degc[4 * d + p], 1);
        }
    } else if (bx < nDeg + nX) {
        int i = (bx - nDeg) * 256 + (int)threadIdx.x;
        if (i >= total4) return;
        const float4 v = *(const float4*)(x + (size_t)i * 4);
        half4h h;
        h.x = (_Float16)v.x; h.y = (_Float16)v.y; h.z = (_Float16)v.z; h.w = (_Float16)v.w;
        *(half4h*)(Xh + (size_t)i * 4) = h;
    } else {
        int idx = (bx - nDeg - nX) * 256 + (int)threadIdx.x;
        if (idx >= totalW) return;
        int s = 0;
#pragma unroll
        for (int t = 1; t < 5; ++t)
            if (idx >= S.start[t]) s = t;
        int local = idx - S.start[s];
        int M = S.M[s], K = S.K[s];
        int k = local / M;
        int m = local - k * M;
        S.H[s][(size_t)m * K + k] = (_Float16)S.W[s][local];
    }
}

// ---------------- prep2: unordered segment base allocation over 4N (dst,chunk) entries ----------------
__global__ __launch_bounds__(256) void prep2_kernel(
    const int* __restrict__ degc, int* __restrict__ rowbeg,
    int* __restrict__ cursor, float* __restrict__ dinv, int* __restrict__ tot, int N4) {
    int e = blockIdx.x * 256 + (int)threadIdx.x;
    int lane = (int)threadIdx.x & 63;
    int d = (e < N4) ? degc[e] : 0;
    int incl = d;
#pragma unroll
    for (int off = 1; off < 64; off <<= 1) {
        int t = __shfl_up(incl, off, 64);
        if (lane >= off) incl += t;
    }
    int wsum = __shfl(incl, 63, 64);
    int wbase = 0;
    if (lane == 63) wbase = atomicAdd(tot, wsum);
    wbase = __shfl(wbase, 63, 64);
    int d4 = d;
    d4 += __shfl_xor(d4, 1, 64);
    d4 += __shfl_xor(d4, 2, 64);
    if (e < N4) {
        int b = wbase + incl - d;
        rowbeg[e] = b;
        cursor[e] = b;
        if ((lane & 3) == 0) dinv[e >> 2] = rsqrtf((float)d4 + 1.0f);
    }
}

// ---------------- fp16 MFMA GEMM body ----------------
// r7: vectorized C-write for OUTHALF (r13: ~neutral overall; kept).
template <bool SCALE, bool BIAS, bool RELU, bool OUTHALF>
__device__ __forceinline__ void gemm_body(
    int bxc, int byr, const _Float16* __restrict__ Ah, const _Float16* __restrict__ Bh,
    const float* __restrict__ bias, const float* __restrict__ rowscale,
    float* __restrict__ outF, _Float16* __restrict__ outH, int Nout, int K, int M,
    _Float16* lds) {
    const int tid = threadIdx.x;
    const int bm = byr * 64;
    const int bn = bxc * 128;
    const int wave = tid >> 6, lane = tid & 63;
    const int quad = lane >> 4, c16 = lane & 15;
    const int wn = wave * 32;

    float4v acc[4][2];
#pragma unroll
    for (int a = 0; a < 4; ++a)
#pragma unroll
        for (int b = 0; b < 2; ++b)
#pragma unroll
            for (int r = 0; r < 4; ++r) acc[a][b][r] = 0.0f;

    const int r0 = tid >> 2;
    const int kq0 = (tid & 3) * 8;

    const _Float16* gA  = Ah + (size_t)(bm + r0) * K + kq0;
    const _Float16* gB0 = Bh + (size_t)(bn + r0) * K + kq0;
    const _Float16* gB1 = Bh + (size_t)(bn + r0 + 64) * K + kq0;

    auto issue = [&](int c) {
        _Float16* buf = lds + (size_t)(c & 1) * 6144;
        int k0 = c * 32;
        gld16(gA + k0, buf + (size_t)tid * 8);
        gld16(gB0 + k0, buf + 2048 + (size_t)tid * 8);
        gld16(gB1 + k0, buf + 2048 + (size_t)(tid + 256) * 8);
    };

    issue(0);
    __syncthreads();

    const int nch = K >> 5;
    for (int c = 0; c < nch; ++c) {
        if (c + 1 < nch) issue(c + 1);

        const _Float16* buf = lds + (size_t)(c & 1) * 6144;
        half8 af[4], bf[2];
#pragma unroll
        for (int t = 0; t < 4; ++t)
            af[t] = *(const half8*)&buf[(t * 16 + c16) * 32 + quad * 8];
#pragma unroll
        for (int t = 0; t < 2; ++t)
            bf[t] = *(const half8*)&buf[2048 + (wn + t * 16 + c16) * 32 + quad * 8];
#pragma unroll
        for (int tm = 0; tm < 4; ++tm)
#pragma unroll
            for (int tn = 0; tn < 2; ++tn)
                acc[tm][tn] = __builtin_amdgcn_mfma_f32_16x16x32_f16(af[tm], bf[tn], acc[tm][tn], 0, 0, 0);
        __syncthreads();
    }

    // epilogue: C/D layout col=lane&15, row=quad*4+reg
    if (OUTHALF) {
        const int LDT = 136;  // halves; 272B row stride (16B-aligned)
#pragma unroll
        for (int tm = 0; tm < 4; ++tm) {
#pragma unroll
            for (int tn = 0; tn < 2; ++tn) {
                int coll = wn + tn * 16 + c16;
                float bv = BIAS ? bias[bn + coll] : 0.0f;
#pragma unroll
                for (int r = 0; r < 4; ++r) {
                    int rowl = tm * 16 + quad * 4 + r;
                    float v = acc[tm][tn][r];
                    if (SCALE) v *= rowscale[bm + rowl];   // rows >= Nout read ws pad; discarded below
                    if (BIAS) v += bv;
                    if (RELU) v = fmaxf(v, 0.0f);
                    lds[rowl * LDT + coll] = (_Float16)v;  // 64*136 halves = 17.4KB <= 24KB dbuf
                }
            }
        }
        __syncthreads();
#pragma unroll
        for (int k = 0; k < 4; ++k) {
            int w = tid * 4 + k;        // 0..1023 = 64 rows x 16 half8-words
            int rowl = w >> 4;
            int c8 = (w & 15) * 8;
            int grow = bm + rowl;
            if (grow < Nout)
                *(half8*)(outH + (size_t)grow * M + bn + c8) =
                    *(const half8*)&lds[rowl * LDT + c8];
        }
    } else {
#pragma unroll
        for (int tm = 0; tm < 4; ++tm) {
#pragma unroll
            for (int tn = 0; tn < 2; ++tn) {
                int colg = bn + wn + tn * 16 + c16;
                float bv = BIAS ? bias[colg] : 0.0f;
#pragma unroll
                for (int r = 0; r < 4; ++r) {
                    int row = bm + tm * 16 + quad * 4 + r;
                    if (row >= Nout) continue;
                    float v = acc[tm][tn][r];
                    if (SCALE) v *= rowscale[row];
                    if (BIAS) v += bv;
                    if (RELU) v = fmaxf(v, 0.0f);
                    outF[(size_t)row * M + colg] = v;
                }
            }
        }
    }
}

template <bool SCALE, bool BIAS, bool RELU, bool OUTHALF>
__global__ __launch_bounds__(256, 4) void gemm_std(
    const _Float16* __restrict__ Ah, const _Float16* __restrict__ Bh,
    const float* __restrict__ bias, const float* __restrict__ rowscale,
    float* __restrict__ outF, _Float16* __restrict__ outH, int Nout, int K, int M) {
    __shared__ _Float16 lds[2 * 6144];
    gemm_body<SCALE, BIAS, RELU, OUTHALF>(blockIdx.x, blockIdx.y, Ah, Bh, bias, rowscale,
                                          outF, outH, Nout, K, M, lds);
}

// ---------------- FUSED2: INTERLEAVED fill + layer-0 GEMM ----------------
// r13 insight: 58us = fill(~30) + gemm(~28) SERIALIZED, because blocks 0..nFill-1
// (fill) dispatch before the GEMM blocks -> CUs saturate with fill first, GEMM
// runs after. Fix: interleave roles (every kth block is a GEMM block) so both
// kinds are co-resident from dispatch start; disjoint pipes (fill: VMEM/atomic,
// GEMM: MFMA/LDS) then truly overlap. k = T/nGemm (exact, =5 here); k==0 falls
// back to the old tail layout. GEMM-count below bx is bx/k (blocks at j*k+k-1).
__global__ __launch_bounds__(256, 4) void fill_gemm_kernel(
    const int* __restrict__ src, const int* __restrict__ dst,
    int* __restrict__ cursor, int* __restrict__ col, int E, int nFill, int CH, int RANGE,
    int kIlv,
    const _Float16* __restrict__ Ah, const _Float16* __restrict__ Bh,
    const float* __restrict__ rowscale, _Float16* __restrict__ outH,
    int Nout, int K, int M) {
    __shared__ _Float16 lds[2 * 6144];
    const int bx = blockIdx.x;
    const bool isGemm = (kIlv > 0) ? ((bx % kIlv) == (kIlv - 1)) : (bx >= nFill);
    if (!isGemm) {
        const int fidx = (kIlv > 0) ? (bx - bx / kIlv) : bx;   // 0..nFill-1
        const int g = fidx & (NXCD - 1);     // dst-range group, XCD-affine
        const int rb = fidx >> 3;            // block rank within group
        const int BPG = nFill >> 3;          // blocks per group
        const int lo = g * RANGE, hi = lo + RANGE;
        const int stride = BPG * 256;
        for (int e = rb * 256 + (int)threadIdx.x; e < E; e += stride) {
            int d = __builtin_nontemporal_load(dst + e);
            if (d >= lo && d < hi) {
                int s = __builtin_nontemporal_load(src + e);
                int p = chunk_of(s, CH);
                int pos = atomicAdd(&cursor[4 * d + p], 1);
                col[pos] = s;
            }
        }
    } else {
        const int byr = (kIlv > 0) ? (bx / kIlv) : (bx - nFill);
        gemm_body<true, false, false, true>(0, byr, Ah, Bh, nullptr, rowscale,
                                            nullptr, outH, Nout, K, M, lds);
    }
}

// ---------------- gather: 8-deep MLP, plain loads (r13-verified, best) ----------------
__global__ __launch_bounds__(256) void gather_kernel(
    const _Float16* __restrict__ hs, const int* __restrict__ rowbeg,
    const int* __restrict__ rowend, const int* __restrict__ col,
    const float* __restrict__ dinv, const float* __restrict__ bias,
    _Float16* __restrict__ Ch, int N) {
    long long idx = (long long)blockIdx.x * blockDim.x + threadIdx.x;
    int i = (int)(idx >> 4);
    if (i >= N) return;
    int c = ((int)idx & 15) * 8;

    const int4v rbv = *(const int4v*)(rowbeg + (size_t)4 * i);
    const int4v rev = *(const int4v*)(rowend + (size_t)4 * i);
    int jb[4] = {rbv.x, rbv.y, rbv.z, rbv.w};
    int je[4] = {rev.x, rev.y, rev.z, rev.w};

    const half8 sv = *(const half8*)(hs + (size_t)i * HID + c);  // self-loop
    float ax[8];
#pragma unroll
    for (int r = 0; r < 8; ++r) ax[r] = (float)sv[r];

#pragma unroll
    for (int p = 0; p < 4; ++p) {
        int j = jb[p];
        const int end = je[p];
        for (; j + 8 <= end; j += 8) {
            int s0 = col[j],     s1 = col[j + 1], s2 = col[j + 2], s3 = col[j + 3];
            int s4 = col[j + 4], s5 = col[j + 5], s6 = col[j + 6], s7 = col[j + 7];
            const half8 v0 = *(const half8*)(hs + (size_t)s0 * HID + c);
            const half8 v1 = *(const half8*)(hs + (size_t)s1 * HID + c);
            const half8 v2 = *(const half8*)(hs + (size_t)s2 * HID + c);
            const half8 v3 = *(const half8*)(hs + (size_t)s3 * HID + c);
            const half8 v4 = *(const half8*)(hs + (size_t)s4 * HID + c);
            const half8 v5 = *(const half8*)(hs + (size_t)s5 * HID + c);
            const half8 v6 = *(const half8*)(hs + (size_t)s6 * HID + c);
            const half8 v7 = *(const half8*)(hs + (size_t)s7 * HID + c);
#pragma unroll
            for (int r = 0; r < 8; ++r)
                ax[r] += (((float)v0[r] + (float)v1[r]) + ((float)v2[r] + (float)v3[r])) +
                         (((float)v4[r] + (float)v5[r]) + ((float)v6[r] + (float)v7[r]));
        }
        for (; j + 4 <= end; j += 4) {
            int s0 = col[j], s1 = col[j + 1], s2 = col[j + 2], s3 = col[j + 3];
            const half8 v0 = *(const half8*)(hs + (size_t)s0 * HID + c);
            const half8 v1 = *(const half8*)(hs + (size_t)s1 * HID + c);
            const half8 v2 = *(const half8*)(hs + (size_t)s2 * HID + c);
            const half8 v3 = *(const half8*)(hs + (size_t)s3 * HID + c);
#pragma unroll
            for (int r = 0; r < 8; ++r)
                ax[r] += ((float)v0[r] + (float)v1[r]) + ((float)v2[r] + (float)v3[r]);
        }
        for (; j < end; ++j) {
            int s = col[j];
            const half8 v = *(const half8*)(hs + (size_t)s * HID + c);
#pragma unroll
            for (int r = 0; r < 8; ++r) ax[r] += (float)v[r];
        }
    }

    float di = dinv[i];
    half8 rr;
#pragma unroll
    for (int r = 0; r < 8; ++r)
        rr[r] = (_Float16)fmaxf(ax[r] * di + bias[c + r], 0.0f);
    *(half8*)(Ch + (size_t)i * HID + c) = rr;
}

// ---------------- host launch ----------------

extern "C" void kernel_launch(void* const* d_in, const int* in_sizes, int n_in,
                              void* d_out, int out_size, void* d_ws, size_t ws_size,
                              hipStream_t stream) {
    const float* x   = (const float*)d_in[0];
    const int*   ei  = (const int*)d_in[1];
    const float* Wg0 = (const float*)d_in[2];
    const float* bg0 = (const float*)d_in[3];
    const float* Wg1 = (const float*)d_in[4];
    const float* bg1 = (const float*)d_in[5];
    const float* Wg2 = (const float*)d_in[6];
    const float* bg2 = (const float*)d_in[7];
    const float* Wm0 = (const float*)d_in[8];
    const float* bm0 = (const float*)d_in[9];
    const float* Wm1 = (const float*)d_in[10];
    const float* bm1 = (const float*)d_in[11];
    float* out = (float*)d_out;

    const int N  = in_sizes[0] / HID;   // 50000
    const int E  = in_sizes[1] / 2;     // 800000
    const int M0 = in_sizes[9];         // 512
    const int M1 = in_sizes[11];        // 256
    const int Npad = ((N + 127) / 128) * 128;   // 50048
    const int CH = (N + NCHUNK - 1) / NCHUNK;   // 12500 source rows/chunk
    const int RANGE = (N + NXCD - 1) / NXCD;    // 6250 dst rows/XCD-group
    const int N4 = 4 * N;

    const int* src = ei;
    const int* dst = ei + E;

    char* ws = (char*)d_ws;
    size_t off = 0;
    auto alloc = [&](size_t bytes) {
        void* p = ws + off;
        off += (bytes + 255) & ~(size_t)255;
        return p;
    };
    int* degc   = (int*)alloc((size_t)N4 * 4);
    int* tot    = (int*)alloc(256);
    int* rowbeg = (int*)alloc((size_t)N4 * 4);
    int* cursor = (int*)alloc((size_t)N4 * 4);
    int* colbuf = (int*)alloc((size_t)E * 4);
    float* dinv = (float*)alloc((size_t)N * 4);
    _Float16* WgT[3];
    for (int l = 0; l < 3; ++l)
        WgT[l] = (_Float16*)alloc((size_t)HID * HID * 2);
    _Float16* Wm0T = (_Float16*)alloc((size_t)M0 * HID * 2);
    _Float16* Wm1T = (_Float16*)alloc((size_t)M1 * M0 * 2);
    _Float16* Xh = (_Float16*)alloc((size_t)Npad * HID * 2);
    _Float16* Hs = (_Float16*)alloc((size_t)Npad * HID * 2);
    _Float16* Ch = (_Float16*)alloc((size_t)Npad * HID * 2);
    _Float16* Mh = (_Float16*)alloc((size_t)Npad * M0 * 2);

    (void)hipMemsetAsync(degc, 0, ((char*)tot - (char*)degc) + 256, stream);

    // ---- FUSED1: chunked deg + xconv + wconv ----
    const int nDeg = (E + 255) / 256;
    const int total4 = N * HID / 4;
    const int nX = (total4 + 255) / 256;
    int totalW;
    WSegs S;
    {
        const float* Ws[5] = {Wg0, Wg1, Wg2, Wm0, Wm1};
        _Float16* Hs5[5]   = {WgT[0], WgT[1], WgT[2], Wm0T, Wm1T};
        int Ks[5] = {HID, HID, HID, HID, M0};
        int Ms[5] = {HID, HID, HID, M0, M1};
        int start = 0;
        for (int s = 0; s < 5; ++s) {
            S.W[s] = Ws[s]; S.H[s] = Hs5[s];
            S.K[s] = Ks[s]; S.M[s] = Ms[s]; S.start[s] = start;
            start += Ks[s] * Ms[s];
        }
        totalW = start;
    }
    const int nW = (totalW + 255) / 256;
    fused_prep1<<<nDeg + nX + nW, 256, 0, stream>>>(
        src, dst, degc, E, nDeg, CH, x, Xh, total4, nX, S, totalW);

    // ---- prep2 ----
    prep2_kernel<<<(N4 + 255) / 256, 256, 0, stream>>>(
        degc, rowbeg, cursor, dinv, tot, N4);

    // ---- FUSED2: interleaved XCD-affine fill + layer-0 GEMM ----
    const int nFill = ((nDeg + NXCD - 1) / NXCD) * NXCD;   // 3128, multiple of 8
    const int nGemm = Npad / 64;                           // 782
    const int T = nFill + nGemm;                           // 3910
    const int kIlv = (T % nGemm == 0) ? (T / nGemm) : 0;   // 5 (exact) or fallback
    fill_gemm_kernel<<<T, 256, 0, stream>>>(
        src, dst, cursor, colbuf, E, nFill, CH, RANGE, kIlv,
        Xh, WgT[0], dinv, Hs, N, HID, HID);

    // ---- layer 0 gather, then layers 1,2 ----  (cursor == segment ends after fill)
    const float* bg[3] = {bg0, bg1, bg2};
    long long gatherThreads = (long long)N * 16;
    int gblocks = (int)((gatherThreads + 255) / 256);
    gather_kernel<<<gblocks, 256, 0, stream>>>(
        Hs, rowbeg, cursor, colbuf, dinv, bg[0], Ch, N);
    for (int l = 1; l < 3; ++l) {
        gemm_std<true, false, false, true><<<dim3(1, Npad / 64), 256, 0, stream>>>(
            Ch, WgT[l], nullptr, dinv, nullptr, Hs, N, HID, HID);
        gather_kernel<<<gblocks, 256, 0, stream>>>(
            Hs, rowbeg, cursor, colbuf, dinv, bg[l], Ch, N);
    }

    // ---- MLP head ----
    gemm_std<false, true, true, true><<<dim3(M0 / 128, Npad / 64), 256, 0, stream>>>(
        Ch, Wm0T, bm0, nullptr, nullptr, Mh, N, HID, M0);
    gemm_std<false, true, true, false><<<dim3(M1 / 128, Npad / 64), 256, 0, stream>>>(
        Mh, Wm1T, bm1, nullptr, out, nullptr, N, M0, M1);
}

// Round 15
// 408.537 us; speedup vs baseline: 1.1144x; 1.1144x over previous
//
#include <hip/hip_runtime.h>

#define HID 128
#define NCHUNK 4   // source-node chunks; 12500 rows * 256 B = 3.2 MB < 4 MiB per-XCD L2
#define NXCD 8

typedef _Float16 half8 __attribute__((ext_vector_type(8)));
typedef _Float16 half4h __attribute__((ext_vector_type(4)));
typedef int int4v __attribute__((ext_vector_type(4)));
using float4v = __attribute__((ext_vector_type(4))) float;

// ---- async global->LDS, 16 B per lane (wave-uniform base + lane*16) ----
typedef const __attribute__((address_space(1))) unsigned int* gas_ptr;
typedef __attribute__((address_space(3))) unsigned int* las_ptr;
__device__ __forceinline__ void gld16(const void* g, void* l) {
    __builtin_amdgcn_global_load_lds((gas_ptr)g, (las_ptr)l, 16, 0, 0);
}

__device__ __forceinline__ int chunk_of(int s, int CH) {
    return (s >= CH) + (s >= 2 * CH) + (s >= 3 * CH);
}

// all 5 weight matrices transposed+converted: Wh[m*K+k] = W[k*M+m]
struct WSegs {
    const float* W[5];
    _Float16* H[5];
    int K[5], M[5], start[5];
};

// ---------------- FUSED1: per-(dst,chunk) deg count + x->fp16 + W transpose/convert ----------------
__global__ __launch_bounds__(256) void fused_prep1(
    const int* __restrict__ src, const int* __restrict__ dst,
    int* __restrict__ degc, int E, int nDeg, int CH,
    const float* __restrict__ x, _Float16* __restrict__ Xh, int total4, int nX,
    WSegs S, int totalW) {
    int bx = blockIdx.x;
    if (bx < nDeg) {
        int i = bx * 256 + (int)threadIdx.x;
        if (i < E) {
            int d = dst[i];
            int p = chunk_of(src[i], CH);
            atomicAdd(&degc[4 * d + p], 1);
        }
    } else if (bx < nDeg + nX) {
        int i = (bx - nDeg) * 256 + (int)threadIdx.x;
        if (i >= total4) return;
        const float4 v = *(const float4*)(x + (size_t)i * 4);
        half4h h;
        h.x = (_Float16)v.x; h.y = (_Float16)v.y; h.z = (_Float16)v.z; h.w = (_Float16)v.w;
        *(half4h*)(Xh + (size_t)i * 4) = h;
    } else {
        int idx = (bx - nDeg - nX) * 256 + (int)threadIdx.x;
        if (idx >= totalW) return;
        int s = 0;
#pragma unroll
        for (int t = 1; t < 5; ++t)
            if (idx >= S.start[t]) s = t;
        int local = idx - S.start[s];
        int M = S.M[s], K = S.K[s];
        int k = local / M;
        int m = local - k * M;
        S.H[s][(size_t)m * K + k] = (_Float16)S.W[s][local];
    }
}

// ---------------- prep2: unordered segment base allocation over 4N (dst,chunk) entries ----------------
// Wave-scan over consecutive lanes => entries 4i..4i+3 (one node's 4 chunk
// segments) are allocated CONTIGUOUSLY in chunk order (64%4==0: never straddles
// a wave). The gather exploits this: one merged range [rowbeg[4i], end[4i+3]).
__global__ __launch_bounds__(256) void prep2_kernel(
    const int* __restrict__ degc, int* __restrict__ rowbeg,
    int* __restrict__ cursor, float* __restrict__ dinv, int* __restrict__ tot, int N4) {
    int e = blockIdx.x * 256 + (int)threadIdx.x;
    int lane = (int)threadIdx.x & 63;
    int d = (e < N4) ? degc[e] : 0;
    int incl = d;
#pragma unroll
    for (int off = 1; off < 64; off <<= 1) {
        int t = __shfl_up(incl, off, 64);
        if (lane >= off) incl += t;
    }
    int wsum = __shfl(incl, 63, 64);
    int wbase = 0;
    if (lane == 63) wbase = atomicAdd(tot, wsum);
    wbase = __shfl(wbase, 63, 64);
    int d4 = d;
    d4 += __shfl_xor(d4, 1, 64);
    d4 += __shfl_xor(d4, 2, 64);
    if (e < N4) {
        int b = wbase + incl - d;
        rowbeg[e] = b;
        cursor[e] = b;
        if ((lane & 3) == 0) dinv[e >> 2] = rsqrtf((float)d4 + 1.0f);
    }
}

// ---------------- fp16 MFMA GEMM body ----------------
// r7: vectorized C-write for OUTHALF (r13: ~neutral; kept).
template <bool SCALE, bool BIAS, bool RELU, bool OUTHALF>
__device__ __forceinline__ void gemm_body(
    int bxc, int byr, const _Float16* __restrict__ Ah, const _Float16* __restrict__ Bh,
    const float* __restrict__ bias, const float* __restrict__ rowscale,
    float* __restrict__ outF, _Float16* __restrict__ outH, int Nout, int K, int M,
    _Float16* lds) {
    const int tid = threadIdx.x;
    const int bm = byr * 64;
    const int bn = bxc * 128;
    const int wave = tid >> 6, lane = tid & 63;
    const int quad = lane >> 4, c16 = lane & 15;
    const int wn = wave * 32;

    float4v acc[4][2];
#pragma unroll
    for (int a = 0; a < 4; ++a)
#pragma unroll
        for (int b = 0; b < 2; ++b)
#pragma unroll
            for (int r = 0; r < 4; ++r) acc[a][b][r] = 0.0f;

    const int r0 = tid >> 2;
    const int kq0 = (tid & 3) * 8;

    const _Float16* gA  = Ah + (size_t)(bm + r0) * K + kq0;
    const _Float16* gB0 = Bh + (size_t)(bn + r0) * K + kq0;
    const _Float16* gB1 = Bh + (size_t)(bn + r0 + 64) * K + kq0;

    auto issue = [&](int c) {
        _Float16* buf = lds + (size_t)(c & 1) * 6144;
        int k0 = c * 32;
        gld16(gA + k0, buf + (size_t)tid * 8);
        gld16(gB0 + k0, buf + 2048 + (size_t)tid * 8);
        gld16(gB1 + k0, buf + 2048 + (size_t)(tid + 256) * 8);
    };

    issue(0);
    __syncthreads();

    const int nch = K >> 5;
    for (int c = 0; c < nch; ++c) {
        if (c + 1 < nch) issue(c + 1);

        const _Float16* buf = lds + (size_t)(c & 1) * 6144;
        half8 af[4], bf[2];
#pragma unroll
        for (int t = 0; t < 4; ++t)
            af[t] = *(const half8*)&buf[(t * 16 + c16) * 32 + quad * 8];
#pragma unroll
        for (int t = 0; t < 2; ++t)
            bf[t] = *(const half8*)&buf[2048 + (wn + t * 16 + c16) * 32 + quad * 8];
#pragma unroll
        for (int tm = 0; tm < 4; ++tm)
#pragma unroll
            for (int tn = 0; tn < 2; ++tn)
                acc[tm][tn] = __builtin_amdgcn_mfma_f32_16x16x32_f16(af[tm], bf[tn], acc[tm][tn], 0, 0, 0);
        __syncthreads();
    }

    // epilogue: C/D layout col=lane&15, row=quad*4+reg
    if (OUTHALF) {
        const int LDT = 136;  // halves; 272B row stride (16B-aligned)
#pragma unroll
        for (int tm = 0; tm < 4; ++tm) {
#pragma unroll
            for (int tn = 0; tn < 2; ++tn) {
                int coll = wn + tn * 16 + c16;
                float bv = BIAS ? bias[bn + coll] : 0.0f;
#pragma unroll
                for (int r = 0; r < 4; ++r) {
                    int rowl = tm * 16 + quad * 4 + r;
                    float v = acc[tm][tn][r];
                    if (SCALE) v *= rowscale[bm + rowl];   // rows >= Nout read ws pad; discarded below
                    if (BIAS) v += bv;
                    if (RELU) v = fmaxf(v, 0.0f);
                    lds[rowl * LDT + coll] = (_Float16)v;  // 64*136 halves = 17.4KB <= 24KB dbuf
                }
            }
        }
        __syncthreads();
#pragma unroll
        for (int k = 0; k < 4; ++k) {
            int w = tid * 4 + k;        // 0..1023 = 64 rows x 16 half8-words
            int rowl = w >> 4;
            int c8 = (w & 15) * 8;
            int grow = bm + rowl;
            if (grow < Nout)
                *(half8*)(outH + (size_t)grow * M + bn + c8) =
                    *(const half8*)&lds[rowl * LDT + c8];
        }
    } else {
#pragma unroll
        for (int tm = 0; tm < 4; ++tm) {
#pragma unroll
            for (int tn = 0; tn < 2; ++tn) {
                int colg = bn + wn + tn * 16 + c16;
                float bv = BIAS ? bias[colg] : 0.0f;
#pragma unroll
                for (int r = 0; r < 4; ++r) {
                    int row = bm + tm * 16 + quad * 4 + r;
                    if (row >= Nout) continue;
                    float v = acc[tm][tn][r];
                    if (SCALE) v *= rowscale[row];
                    if (BIAS) v += bv;
                    if (RELU) v = fmaxf(v, 0.0f);
                    outF[(size_t)row * M + colg] = v;
                }
            }
        }
    }
}

template <bool SCALE, bool BIAS, bool RELU, bool OUTHALF>
__global__ __launch_bounds__(256, 4) void gemm_std(
    const _Float16* __restrict__ Ah, const _Float16* __restrict__ Bh,
    const float* __restrict__ bias, const float* __restrict__ rowscale,
    float* __restrict__ outF, _Float16* __restrict__ outH, int Nout, int K, int M) {
    __shared__ _Float16 lds[2 * 6144];
    gemm_body<SCALE, BIAS, RELU, OUTHALF>(blockIdx.x, blockIdx.y, Ah, Bh, bias, rowscale,
                                          outF, outH, Nout, K, M, lds);
}

// ---------------- FUSED2: serial XCD-affine fill + layer-0 GEMM (r13 layout RESTORED) ----------------
// r14 interleave: (a) broke affinity (g from compacted idx != raw-bx XCD; WRITE
// 43->65MB — confirms raw-bx&7 round-robin heuristic), (b) overlap gave 0 even
// co-resident: fill is L2<->HBM scattered-writeback-BW-bound, GEMM competes for
// the same resource. Co-scheduling twice-falsified; serial r13 form (58us) kept.
__global__ __launch_bounds__(256, 4) void fill_gemm_kernel(
    const int* __restrict__ src, const int* __restrict__ dst,
    int* __restrict__ cursor, int* __restrict__ col, int E, int nFill, int CH, int RANGE,
    const _Float16* __restrict__ Ah, const _Float16* __restrict__ Bh,
    const float* __restrict__ rowscale, _Float16* __restrict__ outH,
    int Nout, int K, int M) {
    __shared__ _Float16 lds[2 * 6144];
    int bx = blockIdx.x;
    if (bx < nFill) {
        const int g = bx & (NXCD - 1);       // dst-range group, XCD-affine (RAW blockIdx)
        const int rb = bx >> 3;              // block rank within group
        const int BPG = nFill >> 3;          // blocks per group
        const int lo = g * RANGE, hi = lo + RANGE;
        const int stride = BPG * 256;
        for (int e = rb * 256 + (int)threadIdx.x; e < E; e += stride) {
            int d = __builtin_nontemporal_load(dst + e);
            if (d >= lo && d < hi) {
                int s = __builtin_nontemporal_load(src + e);
                int p = chunk_of(s, CH);
                int pos = atomicAdd(&cursor[4 * d + p], 1);
                col[pos] = s;
            }
        }
    } else {
        gemm_body<true, false, false, true>(0, bx - nFill, Ah, Bh, nullptr, rowscale,
                                            nullptr, outH, Nout, K, M, lds);
    }
}

// ---------------- gather: MERGED chunk segments, 8-deep MLP ----------------
// r13 gathers ~55us: mean deg 16 split over 4 chunks -> mean segment 4 edges ->
// the 8-deep loop never engages (runs in 4-deep/scalar tails, no MLP). Fix:
// node i's 4 segments are CONTIGUOUS in chunk order (prep2 wave-scan property),
// so iterate ONE merged range [rowbeg[4i], end[4i+3]) -> full deg~16 stream,
// 2x 8-deep bursts/node. Chunk-ordered layout preserved -> L2 locality intact.
__global__ __launch_bounds__(256) void gather_kernel(
    const _Float16* __restrict__ hs, const int* __restrict__ rowbeg,
    const int* __restrict__ rowend, const int* __restrict__ col,
    const float* __restrict__ dinv, const float* __restrict__ bias,
    _Float16* __restrict__ Ch, int N) {
    long long idx = (long long)blockIdx.x * blockDim.x + threadIdx.x;
    int i = (int)(idx >> 4);
    if (i >= N) return;
    int c = ((int)idx & 15) * 8;

    int j = rowbeg[4 * i];            // start of chunk-0 segment
    const int end = rowend[4 * i + 3]; // end of chunk-3 segment (cursor post-fill)

    const half8 sv = *(const half8*)(hs + (size_t)i * HID + c);  // self-loop
    float ax[8];
#pragma unroll
    for (int r = 0; r < 8; ++r) ax[r] = (float)sv[r];

    for (; j + 8 <= end; j += 8) {
        int s0 = col[j],     s1 = col[j + 1], s2 = col[j + 2], s3 = col[j + 3];
        int s4 = col[j + 4], s5 = col[j + 5], s6 = col[j + 6], s7 = col[j + 7];
        const half8 v0 = *(const half8*)(hs + (size_t)s0 * HID + c);
        const half8 v1 = *(const half8*)(hs + (size_t)s1 * HID + c);
        const half8 v2 = *(const half8*)(hs + (size_t)s2 * HID + c);
        const half8 v3 = *(const half8*)(hs + (size_t)s3 * HID + c);
        const half8 v4 = *(const half8*)(hs + (size_t)s4 * HID + c);
        const half8 v5 = *(const half8*)(hs + (size_t)s5 * HID + c);
        const half8 v6 = *(const half8*)(hs + (size_t)s6 * HID + c);
        const half8 v7 = *(const half8*)(hs + (size_t)s7 * HID + c);
#pragma unroll
        for (int r = 0; r < 8; ++r)
            ax[r] += (((float)v0[r] + (float)v1[r]) + ((float)v2[r] + (float)v3[r])) +
                     (((float)v4[r] + (float)v5[r]) + ((float)v6[r] + (float)v7[r]));
    }
    for (; j + 4 <= end; j += 4) {
        int s0 = col[j], s1 = col[j + 1], s2 = col[j + 2], s3 = col[j + 3];
        const half8 v0 = *(const half8*)(hs + (size_t)s0 * HID + c);
        const half8 v1 = *(const half8*)(hs + (size_t)s1 * HID + c);
        const half8 v2 = *(const half8*)(hs + (size_t)s2 * HID + c);
        const half8 v3 = *(const half8*)(hs + (size_t)s3 * HID + c);
#pragma unroll
        for (int r = 0; r < 8; ++r)
            ax[r] += ((float)v0[r] + (float)v1[r]) + ((float)v2[r] + (float)v3[r]);
    }
    for (; j < end; ++j) {
        int s = col[j];
        const half8 v = *(const half8*)(hs + (size_t)s * HID + c);
#pragma unroll
        for (int r = 0; r < 8; ++r) ax[r] += (float)v[r];
    }

    float di = dinv[i];
    half8 rr;
#pragma unroll
    for (int r = 0; r < 8; ++r)
        rr[r] = (_Float16)fmaxf(ax[r] * di + bias[c + r], 0.0f);
    *(half8*)(Ch + (size_t)i * HID + c) = rr;
}

// ---------------- host launch ----------------

extern "C" void kernel_launch(void* const* d_in, const int* in_sizes, int n_in,
                              void* d_out, int out_size, void* d_ws, size_t ws_size,
                              hipStream_t stream) {
    const float* x   = (const float*)d_in[0];
    const int*   ei  = (const int*)d_in[1];
    const float* Wg0 = (const float*)d_in[2];
    const float* bg0 = (const float*)d_in[3];
    const float* Wg1 = (const float*)d_in[4];
    const float* bg1 = (const float*)d_in[5];
    const float* Wg2 = (const float*)d_in[6];
    const float* bg2 = (const float*)d_in[7];
    const float* Wm0 = (const float*)d_in[8];
    const float* bm0 = (const float*)d_in[9];
    const float* Wm1 = (const float*)d_in[10];
    const float* bm1 = (const float*)d_in[11];
    float* out = (float*)d_out;

    const int N  = in_sizes[0] / HID;   // 50000
    const int E  = in_sizes[1] / 2;     // 800000
    const int M0 = in_sizes[9];         // 512
    const int M1 = in_sizes[11];        // 256
    const int Npad = ((N + 127) / 128) * 128;   // 50048
    const int CH = (N + NCHUNK - 1) / NCHUNK;   // 12500 source rows/chunk
    const int RANGE = (N + NXCD - 1) / NXCD;    // 6250 dst rows/XCD-group
    const int N4 = 4 * N;

    const int* src = ei;
    const int* dst = ei + E;

    char* ws = (char*)d_ws;
    size_t off = 0;
    auto alloc = [&](size_t bytes) {
        void* p = ws + off;
        off += (bytes + 255) & ~(size_t)255;
        return p;
    };
    int* degc   = (int*)alloc((size_t)N4 * 4);
    int* tot    = (int*)alloc(256);
    int* rowbeg = (int*)alloc((size_t)N4 * 4);
    int* cursor = (int*)alloc((size_t)N4 * 4);
    int* colbuf = (int*)alloc((size_t)E * 4);
    float* dinv = (float*)alloc((size_t)N * 4);
    _Float16* WgT[3];
    for (int l = 0; l < 3; ++l)
        WgT[l] = (_Float16*)alloc((size_t)HID * HID * 2);
    _Float16* Wm0T = (_Float16*)alloc((size_t)M0 * HID * 2);
    _Float16* Wm1T = (_Float16*)alloc((size_t)M1 * M0 * 2);
    _Float16* Xh = (_Float16*)alloc((size_t)Npad * HID * 2);
    _Float16* Hs = (_Float16*)alloc((size_t)Npad * HID * 2);
    _Float16* Ch = (_Float16*)alloc((size_t)Npad * HID * 2);
    _Float16* Mh = (_Float16*)alloc((size_t)Npad * M0 * 2);

    (void)hipMemsetAsync(degc, 0, ((char*)tot - (char*)degc) + 256, stream);

    // ---- FUSED1: chunked deg + xconv + wconv ----
    const int nDeg = (E + 255) / 256;
    const int total4 = N * HID / 4;
    const int nX = (total4 + 255) / 256;
    int totalW;
    WSegs S;
    {
        const float* Ws[5] = {Wg0, Wg1, Wg2, Wm0, Wm1};
        _Float16* Hs5[5]   = {WgT[0], WgT[1], WgT[2], Wm0T, Wm1T};
        int Ks[5] = {HID, HID, HID, HID, M0};
        int Ms[5] = {HID, HID, HID, M0, M1};
        int start = 0;
        for (int s = 0; s < 5; ++s) {
            S.W[s] = Ws[s]; S.H[s] = Hs5[s];
            S.K[s] = Ks[s]; S.M[s] = Ms[s]; S.start[s] = start;
            start += Ks[s] * Ms[s];
        }
        totalW = start;
    }
    const int nW = (totalW + 255) / 256;
    fused_prep1<<<nDeg + nX + nW, 256, 0, stream>>>(
        src, dst, degc, E, nDeg, CH, x, Xh, total4, nX, S, totalW);

    // ---- prep2 ----
    prep2_kernel<<<(N4 + 255) / 256, 256, 0, stream>>>(
        degc, rowbeg, cursor, dinv, tot, N4);

    // ---- FUSED2: serial XCD-affine fill + layer-0 GEMM (r13 layout) ----
    const int nFill = ((nDeg + NXCD - 1) / NXCD) * NXCD;   // 3128, multiple of 8
    fill_gemm_kernel<<<nFill + Npad / 64, 256, 0, stream>>>(
        src, dst, cursor, colbuf, E, nFill, CH, RANGE,
        Xh, WgT[0], dinv, Hs, N, HID, HID);

    // ---- layer 0 gather, then layers 1,2 ----  (cursor == segment ends after fill)
    const float* bg[3] = {bg0, bg1, bg2};
    long long gatherThreads = (long long)N * 16;
    int gblocks = (int)((gatherThreads + 255) / 256);
    gather_kernel<<<gblocks, 256, 0, stream>>>(
        Hs, rowbeg, cursor, colbuf, dinv, bg[0], Ch, N);
    for (int l = 1; l < 3; ++l) {
        gemm_std<true, false, false, true><<<dim3(1, Npad / 64), 256, 0, stream>>>(
            Ch, WgT[l], nullptr, dinv, nullptr, Hs, N, HID, HID);
        gather_kernel<<<gblocks, 256, 0, stream>>>(
            Hs, rowbeg, cursor, colbuf, dinv, bg[l], Ch, N);
    }

    // ---- MLP head ----
    gemm_std<false, true, true, true><<<dim3(M0 / 128, Npad / 64), 256, 0, stream>>>(
        Ch, Wm0T, bm0, nullptr, nullptr, Mh, N, HID, M0);
    gemm_std<false, true, true, false><<<dim3(M1 / 128, Npad / 64), 256, 0, stream>>>(
        Mh, Wm1T, bm1, nullptr, out, nullptr, N, M0, M1);
}

// Round 18
// 399.831 us; speedup vs baseline: 1.1386x; 1.0218x over previous
//
#include <hip/hip_runtime.h>

#define HID 128
#define NCHUNK 4   // source-node chunks; 12500 rows * 256 B = 3.2 MB < 4 MiB per-XCD L2
#define NXCD 8

typedef _Float16 half8 __attribute__((ext_vector_type(8)));
typedef _Float16 half4h __attribute__((ext_vector_type(4)));
typedef int int4v __attribute__((ext_vector_type(4)));
using float4v = __attribute__((ext_vector_type(4))) float;

// ---- async global->LDS, 16 B per lane (wave-uniform base + lane*16) ----
typedef const __attribute__((address_space(1))) unsigned int* gas_ptr;
typedef __attribute__((address_space(3))) unsigned int* las_ptr;
__device__ __forceinline__ void gld16(const void* g, void* l) {
    __builtin_amdgcn_global_load_lds((gas_ptr)g, (las_ptr)l, 16, 0, 0);
}

__device__ __forceinline__ int chunk_of(int s, int CH) {
    return (s >= CH) + (s >= 2 * CH) + (s >= 3 * CH);
}

// all 5 weight matrices transposed+converted: Wh[m*K+k] = W[k*M+m]
struct WSegs {
    const float* W[5];
    _Float16* H[5];
    int K[5], M[5], start[5];
};

// ---------------- FUSED1: per-(dst,chunk) deg count + x->fp16 + W transpose/convert ----------------
__global__ __launch_bounds__(256) void fused_prep1(
    const int* __restrict__ src, const int* __restrict__ dst,
    int* __restrict__ degc, int E, int nDeg, int CH,
    const float* __restrict__ x, _Float16* __restrict__ Xh, int total4, int nX,
    WSegs S, int totalW) {
    int bx = blockIdx.x;
    if (bx < nDeg) {
        int i = bx * 256 + (int)threadIdx.x;
        if (i < E) {
            int d = dst[i];
            int p = chunk_of(src[i], CH);
            atomicAdd(&degc[4 * d + p], 1);
        }
    } else if (bx < nDeg + nX) {
        int i = (bx - nDeg) * 256 + (int)threadIdx.x;
        if (i >= total4) return;
        const float4 v = *(const float4*)(x + (size_t)i * 4);
        half4h h;
        h.x = (_Float16)v.x; h.y = (_Float16)v.y; h.z = (_Float16)v.z; h.w = (_Float16)v.w;
        *(half4h*)(Xh + (size_t)i * 4) = h;
    } else {
        int idx = (bx - nDeg - nX) * 256 + (int)threadIdx.x;
        if (idx >= totalW) return;
        int s = 0;
#pragma unroll
        for (int t = 1; t < 5; ++t)
            if (idx >= S.start[t]) s = t;
        int local = idx - S.start[s];
        int M = S.M[s], K = S.K[s];
        int k = local / M;
        int m = local - k * M;
        S.H[s][(size_t)m * K + k] = (_Float16)S.W[s][local];
    }
}

// ---------------- prep2: unordered segment base allocation over 4N (dst,chunk) entries ----------------
// Wave-scan over consecutive lanes => entries 4i..4i+3 (one node's 4 chunk
// segments) are allocated CONTIGUOUSLY in chunk order (64%4==0: never straddles
// a wave). The gather exploits this: one merged range [rowbeg[4i], end[4i+3]).
__global__ __launch_bounds__(256) void prep2_kernel(
    const int* __restrict__ degc, int* __restrict__ rowbeg,
    int* __restrict__ cursor, float* __restrict__ dinv, int* __restrict__ tot, int N4) {
    int e = blockIdx.x * 256 + (int)threadIdx.x;
    int lane = (int)threadIdx.x & 63;
    int d = (e < N4) ? degc[e] : 0;
    int incl = d;
#pragma unroll
    for (int off = 1; off < 64; off <<= 1) {
        int t = __shfl_up(incl, off, 64);
        if (lane >= off) incl += t;
    }
    int wsum = __shfl(incl, 63, 64);
    int wbase = 0;
    if (lane == 63) wbase = atomicAdd(tot, wsum);
    wbase = __shfl(wbase, 63, 64);
    int d4 = d;
    d4 += __shfl_xor(d4, 1, 64);
    d4 += __shfl_xor(d4, 2, 64);
    if (e < N4) {
        int b = wbase + incl - d;
        rowbeg[e] = b;
        cursor[e] = b;
        if ((lane & 3) == 0) dinv[e >> 2] = rsqrtf((float)d4 + 1.0f);
    }
}

// ---------------- fp16 MFMA GEMM body ----------------
// r7: vectorized C-write for OUTHALF (r13: ~neutral; kept).
template <bool SCALE, bool BIAS, bool RELU, bool OUTHALF>
__device__ __forceinline__ void gemm_body(
    int bxc, int byr, const _Float16* __restrict__ Ah, const _Float16* __restrict__ Bh,
    const float* __restrict__ bias, const float* __restrict__ rowscale,
    float* __restrict__ outF, _Float16* __restrict__ outH, int Nout, int K, int M,
    _Float16* lds) {
    const int tid = threadIdx.x;
    const int bm = byr * 64;
    const int bn = bxc * 128;
    const int wave = tid >> 6, lane = tid & 63;
    const int quad = lane >> 4, c16 = lane & 15;
    const int wn = wave * 32;

    float4v acc[4][2];
#pragma unroll
    for (int a = 0; a < 4; ++a)
#pragma unroll
        for (int b = 0; b < 2; ++b)
#pragma unroll
            for (int r = 0; r < 4; ++r) acc[a][b][r] = 0.0f;

    const int r0 = tid >> 2;
    const int kq0 = (tid & 3) * 8;

    const _Float16* gA  = Ah + (size_t)(bm + r0) * K + kq0;
    const _Float16* gB0 = Bh + (size_t)(bn + r0) * K + kq0;
    const _Float16* gB1 = Bh + (size_t)(bn + r0 + 64) * K + kq0;

    auto issue = [&](int c) {
        _Float16* buf = lds + (size_t)(c & 1) * 6144;
        int k0 = c * 32;
        gld16(gA + k0, buf + (size_t)tid * 8);
        gld16(gB0 + k0, buf + 2048 + (size_t)tid * 8);
        gld16(gB1 + k0, buf + 2048 + (size_t)(tid + 256) * 8);
    };

    issue(0);
    __syncthreads();

    const int nch = K >> 5;
    for (int c = 0; c < nch; ++c) {
        if (c + 1 < nch) issue(c + 1);

        const _Float16* buf = lds + (size_t)(c & 1) * 6144;
        half8 af[4], bf[2];
#pragma unroll
        for (int t = 0; t < 4; ++t)
            af[t] = *(const half8*)&buf[(t * 16 + c16) * 32 + quad * 8];
#pragma unroll
        for (int t = 0; t < 2; ++t)
            bf[t] = *(const half8*)&buf[2048 + (wn + t * 16 + c16) * 32 + quad * 8];
#pragma unroll
        for (int tm = 0; tm < 4; ++tm)
#pragma unroll
            for (int tn = 0; tn < 2; ++tn)
                acc[tm][tn] = __builtin_amdgcn_mfma_f32_16x16x32_f16(af[tm], bf[tn], acc[tm][tn], 0, 0, 0);
        __syncthreads();
    }

    // epilogue: C/D layout col=lane&15, row=quad*4+reg
    if (OUTHALF) {
        const int LDT = 136;  // halves; 272B row stride (16B-aligned)
#pragma unroll
        for (int tm = 0; tm < 4; ++tm) {
#pragma unroll
            for (int tn = 0; tn < 2; ++tn) {
                int coll = wn + tn * 16 + c16;
                float bv = BIAS ? bias[bn + coll] : 0.0f;
#pragma unroll
                for (int r = 0; r < 4; ++r) {
                    int rowl = tm * 16 + quad * 4 + r;
                    float v = acc[tm][tn][r];
                    if (SCALE) v *= rowscale[bm + rowl];   // rows >= Nout read ws pad; discarded below
                    if (BIAS) v += bv;
                    if (RELU) v = fmaxf(v, 0.0f);
                    lds[rowl * LDT + coll] = (_Float16)v;  // 64*136 halves = 17.4KB <= 24KB dbuf
                }
            }
        }
        __syncthreads();
#pragma unroll
        for (int k = 0; k < 4; ++k) {
            int w = tid * 4 + k;        // 0..1023 = 64 rows x 16 half8-words
            int rowl = w >> 4;
            int c8 = (w & 15) * 8;
            int grow = bm + rowl;
            if (grow < Nout)
                *(half8*)(outH + (size_t)grow * M + bn + c8) =
                    *(const half8*)&lds[rowl * LDT + c8];
        }
    } else {
#pragma unroll
        for (int tm = 0; tm < 4; ++tm) {
#pragma unroll
            for (int tn = 0; tn < 2; ++tn) {
                int colg = bn + wn + tn * 16 + c16;
                float bv = BIAS ? bias[colg] : 0.0f;
#pragma unroll
                for (int r = 0; r < 4; ++r) {
                    int row = bm + tm * 16 + quad * 4 + r;
                    if (row >= Nout) continue;
                    float v = acc[tm][tn][r];
                    if (SCALE) v *= rowscale[row];
                    if (BIAS) v += bv;
                    if (RELU) v = fmaxf(v, 0.0f);
                    outF[(size_t)row * M + colg] = v;
                }
            }
        }
    }
}

template <bool SCALE, bool BIAS, bool RELU, bool OUTHALF>
__global__ __launch_bounds__(256, 4) void gemm_std(
    const _Float16* __restrict__ Ah, const _Float16* __restrict__ Bh,
    const float* __restrict__ bias, const float* __restrict__ rowscale,
    float* __restrict__ outF, _Float16* __restrict__ outH, int Nout, int K, int M) {
    __shared__ _Float16 lds[2 * 6144];
    gemm_body<SCALE, BIAS, RELU, OUTHALF>(blockIdx.x, blockIdx.y, Ah, Bh, bias, rowscale,
                                          outF, outH, Nout, K, M, lds);
}

// ---------------- FUSED2: serial XCD-affine fill + layer-0 GEMM ----------------
// r16 change: PLAIN loads for the edge-list scan (NT hints removed). NT was
// added in r4 when the scan was single-pass; with the 8x dst-range re-scan,
// NT's evict-first policy defeats L3 on the 7 redundant passes (FETCH 31.5MB
// vs ~19MB logical -> ~half the re-reads pay ~900cyc HBM latency; fill profile
// is all-pipes-idle = latency-bound). Serial layout kept (overlap twice-
// falsified r14); XCD affinity from RAW blockIdx (r14 lesson).
__global__ __launch_bounds__(256, 4) void fill_gemm_kernel(
    const int* __restrict__ src, const int* __restrict__ dst,
    int* __restrict__ cursor, int* __restrict__ col, int E, int nFill, int CH, int RANGE,
    const _Float16* __restrict__ Ah, const _Float16* __restrict__ Bh,
    const float* __restrict__ rowscale, _Float16* __restrict__ outH,
    int Nout, int K, int M) {
    __shared__ _Float16 lds[2 * 6144];
    int bx = blockIdx.x;
    if (bx < nFill) {
        const int g = bx & (NXCD - 1);       // dst-range group, XCD-affine (RAW blockIdx)
        const int rb = bx >> 3;              // block rank within group
        const int BPG = nFill >> 3;          // blocks per group
        const int lo = g * RANGE, hi = lo + RANGE;
        const int stride = BPG * 256;
        for (int e = rb * 256 + (int)threadIdx.x; e < E; e += stride) {
            int d = dst[e];
            if (d >= lo && d < hi) {
                int s = src[e];
                int p = chunk_of(s, CH);
                int pos = atomicAdd(&cursor[4 * d + p], 1);
                col[pos] = s;
            }
        }
    } else {
        gemm_body<true, false, false, true>(0, bx - nFill, Ah, Bh, nullptr, rowscale,
                                            nullptr, outH, Nout, K, M, lds);
    }
}

// ---------------- gather: MERGED chunk segments, 8-deep MLP (r15-verified) ----------------
// Node i's 4 chunk segments are contiguous in chunk order (prep2 wave-scan
// property) -> one merged range [rowbeg[4i], end[4i+3]): full deg~16 stream,
// 8-deep bursts engage (r15: -35us). Chunk-ordered col preserves L2 locality.
__global__ __launch_bounds__(256) void gather_kernel(
    const _Float16* __restrict__ hs, const int* __restrict__ rowbeg,
    const int* __restrict__ rowend, const int* __restrict__ col,
    const float* __restrict__ dinv, const float* __restrict__ bias,
    _Float16* __restrict__ Ch, int N) {
    long long idx = (long long)blockIdx.x * blockDim.x + threadIdx.x;
    int i = (int)(idx >> 4);
    if (i >= N) return;
    int c = ((int)idx & 15) * 8;

    int j = rowbeg[4 * i];             // start of chunk-0 segment
    const int end = rowend[4 * i + 3]; // end of chunk-3 segment (cursor post-fill)

    const half8 sv = *(const half8*)(hs + (size_t)i * HID + c);  // self-loop
    float ax[8];
#pragma unroll
    for (int r = 0; r < 8; ++r) ax[r] = (float)sv[r];

    for (; j + 8 <= end; j += 8) {
        int s0 = col[j],     s1 = col[j + 1], s2 = col[j + 2], s3 = col[j + 3];
        int s4 = col[j + 4], s5 = col[j + 5], s6 = col[j + 6], s7 = col[j + 7];
        const half8 v0 = *(const half8*)(hs + (size_t)s0 * HID + c);
        const half8 v1 = *(const half8*)(hs + (size_t)s1 * HID + c);
        const half8 v2 = *(const half8*)(hs + (size_t)s2 * HID + c);
        const half8 v3 = *(const half8*)(hs + (size_t)s3 * HID + c);
        const half8 v4 = *(const half8*)(hs + (size_t)s4 * HID + c);
        const half8 v5 = *(const half8*)(hs + (size_t)s5 * HID + c);
        const half8 v6 = *(const half8*)(hs + (size_t)s6 * HID + c);
        const half8 v7 = *(const half8*)(hs + (size_t)s7 * HID + c);
#pragma unroll
        for (int r = 0; r < 8; ++r)
            ax[r] += (((float)v0[r] + (float)v1[r]) + ((float)v2[r] + (float)v3[r])) +
                     (((float)v4[r] + (float)v5[r]) + ((float)v6[r] + (float)v7[r]));
    }
    for (; j + 4 <= end; j += 4) {
        int s0 = col[j], s1 = col[j + 1], s2 = col[j + 2], s3 = col[j + 3];
        const half8 v0 = *(const half8*)(hs + (size_t)s0 * HID + c);
        const half8 v1 = *(const half8*)(hs + (size_t)s1 * HID + c);
        const half8 v2 = *(const half8*)(hs + (size_t)s2 * HID + c);
        const half8 v3 = *(const half8*)(hs + (size_t)s3 * HID + c);
#pragma unroll
        for (int r = 0; r < 8; ++r)
            ax[r] += ((float)v0[r] + (float)v1[r]) + ((float)v2[r] + (float)v3[r]);
    }
    for (; j < end; ++j) {
        int s = col[j];
        const half8 v = *(const half8*)(hs + (size_t)s * HID + c);
#pragma unroll
        for (int r = 0; r < 8; ++r) ax[r] += (float)v[r];
    }

    float di = dinv[i];
    half8 rr;
#pragma unroll
    for (int r = 0; r < 8; ++r)
        rr[r] = (_Float16)fmaxf(ax[r] * di + bias[c + r], 0.0f);
    *(half8*)(Ch + (size_t)i * HID + c) = rr;
}

// ---------------- host launch ----------------

extern "C" void kernel_launch(void* const* d_in, const int* in_sizes, int n_in,
                              void* d_out, int out_size, void* d_ws, size_t ws_size,
                              hipStream_t stream) {
    const float* x   = (const float*)d_in[0];
    const int*   ei  = (const int*)d_in[1];
    const float* Wg0 = (const float*)d_in[2];
    const float* bg0 = (const float*)d_in[3];
    const float* Wg1 = (const float*)d_in[4];
    const float* bg1 = (const float*)d_in[5];
    const float* Wg2 = (const float*)d_in[6];
    const float* bg2 = (const float*)d_in[7];
    const float* Wm0 = (const float*)d_in[8];
    const float* bm0 = (const float*)d_in[9];
    const float* Wm1 = (const float*)d_in[10];
    const float* bm1 = (const float*)d_in[11];
    float* out = (float*)d_out;

    const int N  = in_sizes[0] / HID;   // 50000
    const int E  = in_sizes[1] / 2;     // 800000
    const int M0 = in_sizes[9];         // 512
    const int M1 = in_sizes[11];        // 256
    const int Npad = ((N + 127) / 128) * 128;   // 50048
    const int CH = (N + NCHUNK - 1) / NCHUNK;   // 12500 source rows/chunk
    const int RANGE = (N + NXCD - 1) / NXCD;    // 6250 dst rows/XCD-group
    const int N4 = 4 * N;

    const int* src = ei;
    const int* dst = ei + E;

    char* ws = (char*)d_ws;
    size_t off = 0;
    auto alloc = [&](size_t bytes) {
        void* p = ws + off;
        off += (bytes + 255) & ~(size_t)255;
        return p;
    };
    int* degc   = (int*)alloc((size_t)N4 * 4);
    int* tot    = (int*)alloc(256);
    int* rowbeg = (int*)alloc((size_t)N4 * 4);
    int* cursor = (int*)alloc((size_t)N4 * 4);
    int* colbuf = (int*)alloc((size_t)E * 4);
    float* dinv = (float*)alloc((size_t)N * 4);
    _Float16* WgT[3];
    for (int l = 0; l < 3; ++l)
        WgT[l] = (_Float16*)alloc((size_t)HID * HID * 2);
    _Float16* Wm0T = (_Float16*)alloc((size_t)M0 * HID * 2);
    _Float16* Wm1T = (_Float16*)alloc((size_t)M1 * M0 * 2);
    _Float16* Xh = (_Float16*)alloc((size_t)Npad * HID * 2);
    _Float16* Hs = (_Float16*)alloc((size_t)Npad * HID * 2);
    _Float16* Ch = (_Float16*)alloc((size_t)Npad * HID * 2);
    _Float16* Mh = (_Float16*)alloc((size_t)Npad * M0 * 2);

    (void)hipMemsetAsync(degc, 0, ((char*)tot - (char*)degc) + 256, stream);

    // ---- FUSED1: chunked deg + xconv + wconv ----
    const int nDeg = (E + 255) / 256;
    const int total4 = N * HID / 4;
    const int nX = (total4 + 255) / 256;
    int totalW;
    WSegs S;
    {
        const float* Ws[5] = {Wg0, Wg1, Wg2, Wm0, Wm1};
        _Float16* Hs5[5]   = {WgT[0], WgT[1], WgT[2], Wm0T, Wm1T};
        int Ks[5] = {HID, HID, HID, HID, M0};
        int Ms[5] = {HID, HID, HID, M0, M1};
        int start = 0;
        for (int s = 0; s < 5; ++s) {
            S.W[s] = Ws[s]; S.H[s] = Hs5[s];
            S.K[s] = Ks[s]; S.M[s] = Ms[s]; S.start[s] = start;
            start += Ks[s] * Ms[s];
        }
        totalW = start;
    }
    const int nW = (totalW + 255) / 256;
    fused_prep1<<<nDeg + nX + nW, 256, 0, stream>>>(
        src, dst, degc, E, nDeg, CH, x, Xh, total4, nX, S, totalW);

    // ---- prep2 ----
    prep2_kernel<<<(N4 + 255) / 256, 256, 0, stream>>>(
        degc, rowbeg, cursor, dinv, tot, N4);

    // ---- FUSED2: serial XCD-affine fill + layer-0 GEMM ----
    const int nFill = ((nDeg + NXCD - 1) / NXCD) * NXCD;   // 3128, multiple of 8
    fill_gemm_kernel<<<nFill + Npad / 64, 256, 0, stream>>>(
        src, dst, cursor, colbuf, E, nFill, CH, RANGE,
        Xh, WgT[0], dinv, Hs, N, HID, HID);

    // ---- layer 0 gather, then layers 1,2 ----  (cursor == segment ends after fill)
    const float* bg[3] = {bg0, bg1, bg2};
    long long gatherThreads = (long long)N * 16;
    int gblocks = (int)((gatherThreads + 255) / 256);
    gather_kernel<<<gblocks, 256, 0, stream>>>(
        Hs, rowbeg, cursor, colbuf, dinv, bg[0], Ch, N);
    for (int l = 1; l < 3; ++l) {
        gemm_std<true, false, false, true><<<dim3(1, Npad / 64), 256, 0, stream>>>(
            Ch, WgT[l], nullptr, dinv, nullptr, Hs, N, HID, HID);
        gather_kernel<<<gblocks, 256, 0, stream>>>(
            Hs, rowbeg, cursor, colbuf, dinv, bg[l], Ch, N);
    }

    // ---- MLP head ----
    gemm_std<false, true, true, true><<<dim3(M0 / 128, Npad / 64), 256, 0, stream>>>(
        Ch, Wm0T, bm0, nullptr, nullptr, Mh, N, HID, M0);
    gemm_std<false, true, true, false><<<dim3(M1 / 128, Npad / 64), 256, 0, stream>>>(
        Mh, Wm1T, bm1, nullptr, out, nullptr, N, M0, M1);
}